// Round 2
// baseline (15136.221 us; speedup 1.0000x reference)
//
#include <hip/hip_runtime.h>
#include <hip/hip_bf16.h>
#include <math.h>

// AdaptiveViT forward. All GEMMs use emulated-fp32 via bf16 hi/lo split + 3x MFMA
// (16x16x32 bf16). Rationale: the adaptive gating ranks are decided by logit gaps
// ~0.25; plain bf16 GEMM noise (~5e-3 on logits) flips ranks for some samples ->
// O(0.5) output error (round-1 absmax 0.676). bf16x3 gives ~1e-4 logit noise.
// Residual stream / LN / softmax / attention in plain fp32 vector math.

using bf16   = __hip_bfloat16;
using short8 = __attribute__((ext_vector_type(8))) short;
using f32x4  = __attribute__((ext_vector_type(4))) float;

#define GLD16(gptr, lptr)                                                            \
    __builtin_amdgcn_global_load_lds((const __attribute__((address_space(1))) void*)(gptr), \
                                     (__attribute__((address_space(3))) void*)(lptr), 16, 0, 0)

// split f32 -> bf16 hi (RNE) + bf16 lo (truncated residual)
__device__ __forceinline__ void split2(float x, short& h, short& l)
{
    unsigned u  = __float_as_uint(x);
    unsigned hr = (u + 0x7fffu + ((u >> 16) & 1u)) & 0xffff0000u;
    h = (short)(hr >> 16);
    float res = x - __uint_as_float(hr);
    l = (short)(__float_as_uint(res) >> 16);
}

// ---------------------------------------------------------------------------
// patch_w is (EMB=768 rows of K=768) i.e. (N,K); transpose to (K,N) f32.
__global__ __launch_bounds__(256) void trans_pw_kernel(const float* __restrict__ W,
                                                       float* __restrict__ Wt)
{
    __shared__ float tile[32][33];
    int n0 = blockIdx.x * 32, k0 = blockIdx.y * 32;
    int c = threadIdx.x & 31, r = threadIdx.x >> 5;
    #pragma unroll
    for (int i = 0; i < 32; i += 8)
        tile[r + i][c] = W[(size_t)(n0 + r + i) * 768 + k0 + c];
    __syncthreads();
    #pragma unroll
    for (int i = 0; i < 32; i += 8)
        Wt[(size_t)(k0 + r + i) * 768 + n0 + c] = tile[c][r + i];
}

// im2col: A[(b*196+p)][c*256+i*16+j] = x[b][c][py*16+i][px*16+j], f32
__global__ void im2col_kernel(const float* __restrict__ x, float* __restrict__ Ap)
{
    int idx = blockIdx.x * 256 + threadIdx.x;
    if (idx >= 6272 * 768) return;
    int k = idx % 768;
    int row = idx / 768;
    int b = row / 196, p = row % 196;
    int py = p / 14, px = p % 14;
    int c = k >> 8, rem = k & 255;
    int i = rem >> 4, j = rem & 15;
    Ap[idx] = x[(((size_t)b * 3 + c) * 224 + py * 16 + i) * 224 + px * 16 + j];
}

// ---------------------------------------------------------------------------
// Emulated-fp32 GEMM: C(MxN) = A(MxK,f32) @ W(KxN,f32) + bias [+resid] [gelu].
// 128x128 tile, BK=32, 4 waves of 64x64. A and W staged f32 via global_load_lds,
// fragments split in-register to bf16 hi/lo, 3 MFMAs per cell.
// A must be padded (rows readable) up to gridDim.y*128 rows; stores masked by M.
template<bool GELU, bool RES>
__global__ __launch_bounds__(256) void gemm32_kernel(const float* __restrict__ A,
                                                     const float* __restrict__ W,
                                                     const float* __restrict__ bias,
                                                     const float* __restrict__ resid,
                                                     float* __restrict__ C,
                                                     int M, int N, int K)
{
    __shared__ __align__(16) float As[128 * 32];   // [m][k]
    __shared__ __align__(16) float Ws[32 * 128];   // [k][n]
    const int tid  = threadIdx.x;
    const int lane = tid & 63;
    const int w    = tid >> 6;
    const int wm   = w >> 1, wn = w & 1;
    const int m0   = blockIdx.y * 128;
    const int n0   = blockIdx.x * 128;
    const int col  = lane & 15;
    const int quad = lane >> 4;

    f32x4 acc[4][4];
    #pragma unroll
    for (int i = 0; i < 4; ++i)
        #pragma unroll
        for (int j = 0; j < 4; ++j) acc[i][j] = (f32x4)0.f;

    // staging lane patterns
    const int a_r  = lane >> 3;          // +row within 8-row group
    const int a_c  = (lane & 7) * 4;     // f32 col
    const int w_r  = lane >> 5;          // +row within 2-row group
    const int w_c  = (lane & 31) * 4;

    const float* Abase = A + (size_t)m0 * K;
    const float* Wbase = W + n0;

    for (int k0 = 0; k0 < K; k0 += 32) {
        #pragma unroll
        for (int i = 0; i < 4; ++i) {
            int ar = w * 32 + i * 8;
            GLD16(Abase + (size_t)(ar + a_r) * K + k0 + a_c, &As[ar * 32]);
            int kr = w * 8 + i * 2;
            GLD16(Wbase + (size_t)(k0 + kr + w_r) * N + w_c, &Ws[kr * 128]);
        }
        __syncthreads();

        short8 ah[4], al[4];
        #pragma unroll
        for (int mi = 0; mi < 4; ++mi) {
            const float* pa = &As[(wm * 64 + mi * 16 + col) * 32 + quad * 8];
            #pragma unroll
            for (int j = 0; j < 8; ++j) {
                short h, l; split2(pa[j], h, l);
                ah[mi][j] = h; al[mi][j] = l;
            }
        }
        const int nlb = wn * 64 + col;
        #pragma unroll
        for (int ni = 0; ni < 4; ++ni) {
            short8 bh, bl;
            #pragma unroll
            for (int j = 0; j < 8; ++j) {
                float x = Ws[(quad * 8 + j) * 128 + nlb + ni * 16];
                short h, l; split2(x, h, l);
                bh[j] = h; bl[j] = l;
            }
            #pragma unroll
            for (int mi = 0; mi < 4; ++mi) {
                acc[mi][ni] = __builtin_amdgcn_mfma_f32_16x16x32_bf16(ah[mi], bh, acc[mi][ni], 0, 0, 0);
                acc[mi][ni] = __builtin_amdgcn_mfma_f32_16x16x32_bf16(ah[mi], bl, acc[mi][ni], 0, 0, 0);
                acc[mi][ni] = __builtin_amdgcn_mfma_f32_16x16x32_bf16(al[mi], bh, acc[mi][ni], 0, 0, 0);
            }
        }
        __syncthreads();
    }

    #pragma unroll
    for (int mi = 0; mi < 4; ++mi) {
        #pragma unroll
        for (int ni = 0; ni < 4; ++ni) {
            int gcol = n0 + wn * 64 + ni * 16 + col;
            float bv = bias[gcol];
            #pragma unroll
            for (int r = 0; r < 4; ++r) {
                int grow = m0 + wm * 64 + mi * 16 + quad * 4 + r;
                if (grow < M) {
                    float v = acc[mi][ni][r] + bv;
                    if (RES) v += resid[(size_t)grow * N + gcol];
                    if (GELU) v = 0.5f * v * (1.f + erff(v * 0.70710678118654752f));
                    C[(size_t)grow * N + gcol] = v;
                }
            }
        }
    }
}

// ---------------------------------------------------------------------------
// LayerNorm over 768, fp32 -> fp32. One wave per row.
__global__ __launch_bounds__(256) void ln_kernel(const float* __restrict__ x,
                                                 const float* __restrict__ g,
                                                 const float* __restrict__ bta,
                                                 float* __restrict__ out, int M)
{
    int row = blockIdx.x * 4 + (threadIdx.x >> 6);
    int lane = threadIdx.x & 63;
    if (row >= M) return;
    const float* xr = x + (size_t)row * 768;
    float vals[12];
    float s = 0.f;
    #pragma unroll
    for (int i = 0; i < 12; ++i) { vals[i] = xr[lane + i * 64]; s += vals[i]; }
    #pragma unroll
    for (int off = 32; off; off >>= 1) s += __shfl_xor(s, off);
    float mean = s * (1.f / 768.f);
    float vs = 0.f;
    #pragma unroll
    for (int i = 0; i < 12; ++i) { float d = vals[i] - mean; vs += d * d; }
    #pragma unroll
    for (int off = 32; off; off >>= 1) vs += __shfl_xor(vs, off);
    float rstd = rsqrtf(vs * (1.f / 768.f) + 1e-5f);
    float* orow = out + (size_t)row * 768;
    #pragma unroll
    for (int i = 0; i < 12; ++i) {
        int c = lane + i * 64;
        orow[c] = (vals[i] - mean) * rstd * g[c] + bta[c];
    }
}

// ---------------------------------------------------------------------------
// Attention: one block per (b, head), fp32, online softmax, one query row/thread.
__global__ __launch_bounds__(256) void attn_kernel(const float* __restrict__ qkv,
                                                   float* __restrict__ O, int S)
{
    __shared__ float Ks[128 * 64];
    __shared__ float Vs[128 * 64];
    int bh = blockIdx.x;
    int b = bh / 12, h = bh % 12;
    const float* base = qkv + (size_t)b * S * 2304;
    int tid = threadIdx.x;
    int r = tid;
    bool act = (r < S);
    float q[64];
    #pragma unroll
    for (int d = 0; d < 64; ++d) q[d] = 0.f;
    if (act) {
        const float4* qp = (const float4*)(base + (size_t)r * 2304 + h * 64);
        #pragma unroll
        for (int d4 = 0; d4 < 16; ++d4) {
            float4 t = qp[d4];
            q[4 * d4] = t.x; q[4 * d4 + 1] = t.y; q[4 * d4 + 2] = t.z; q[4 * d4 + 3] = t.w;
        }
    }
    float o[64];
    #pragma unroll
    for (int d = 0; d < 64; ++d) o[d] = 0.f;
    float m = -1e30f, l = 0.f;

    for (int jc = 0; jc < S; jc += 128) {
        int cnt = min(128, S - jc);
        __syncthreads();
        for (int idx = tid; idx < cnt * 64; idx += 256) {
            int j = idx >> 6, d = idx & 63;
            const float* rp = base + (size_t)(jc + j) * 2304 + h * 64 + d;
            Ks[idx] = rp[768];
            Vs[idx] = rp[1536];
        }
        __syncthreads();
        if (act) {
            for (int j = 0; j < cnt; ++j) {
                const float4* kr = (const float4*)&Ks[j * 64];
                float s0 = 0.f, s1 = 0.f, s2 = 0.f, s3 = 0.f;
                #pragma unroll
                for (int d4 = 0; d4 < 16; ++d4) {
                    float4 kv = kr[d4];
                    s0 += q[4 * d4]     * kv.x;
                    s1 += q[4 * d4 + 1] * kv.y;
                    s2 += q[4 * d4 + 2] * kv.z;
                    s3 += q[4 * d4 + 3] * kv.w;
                }
                float s = ((s0 + s1) + (s2 + s3)) * 0.125f;
                float mn = fmaxf(m, s);
                float alpha = expf(m - mn);
                float p = expf(s - mn);
                l = l * alpha + p;
                m = mn;
                const float4* vr = (const float4*)&Vs[j * 64];
                #pragma unroll
                for (int d4 = 0; d4 < 16; ++d4) {
                    float4 vv = vr[d4];
                    o[4 * d4]     = o[4 * d4]     * alpha + p * vv.x;
                    o[4 * d4 + 1] = o[4 * d4 + 1] * alpha + p * vv.y;
                    o[4 * d4 + 2] = o[4 * d4 + 2] * alpha + p * vv.z;
                    o[4 * d4 + 3] = o[4 * d4 + 3] * alpha + p * vv.w;
                }
            }
        }
    }
    if (act) {
        float inv = 1.f / l;
        float* orow = O + (size_t)(b * S + r) * 768 + h * 64;
        #pragma unroll
        for (int d = 0; d < 64; ++d) orow[d] = o[d] * inv;
    }
}

// ---------------------------------------------------------------------------
__global__ __launch_bounds__(256) void latent_kernel(const float* __restrict__ pe_table,
                                                     const float* __restrict__ budget,
                                                     const float* __restrict__ w1, const float* __restrict__ b1,
                                                     const float* __restrict__ lng, const float* __restrict__ lnb,
                                                     const float* __restrict__ w2, const float* __restrict__ b2,
                                                     float* __restrict__ lat)
{
    int b = blockIdx.x, tid = threadIdx.x;
    __shared__ float pe[256];
    __shared__ float hbuf[768];
    __shared__ float red[256];
    int idx = (int)rintf(budget[b] * 99.f);
    pe[tid] = pe_table[idx * 256 + tid];
    __syncthreads();
    float hv[3];
    #pragma unroll
    for (int t = 0; t < 3; ++t) {
        int colc = tid + t * 256;
        float a = b1[colc];
        for (int k = 0; k < 256; ++k) a += pe[k] * w1[k * 768 + colc];
        hv[t] = 0.5f * a * (1.f + erff(a * 0.70710678118654752f));
    }
    float s = hv[0] + hv[1] + hv[2];
    red[tid] = s; __syncthreads();
    for (int o = 128; o > 0; o >>= 1) { if (tid < o) red[tid] += red[tid + o]; __syncthreads(); }
    float mean = red[0] * (1.f / 768.f);
    __syncthreads();
    float vs = 0.f;
    #pragma unroll
    for (int t = 0; t < 3; ++t) { float d = hv[t] - mean; vs += d * d; }
    red[tid] = vs; __syncthreads();
    for (int o = 128; o > 0; o >>= 1) { if (tid < o) red[tid] += red[tid + o]; __syncthreads(); }
    float rstd = rsqrtf(red[0] * (1.f / 768.f) + 1e-5f);
    __syncthreads();
    #pragma unroll
    for (int t = 0; t < 3; ++t) {
        int colc = tid + t * 256;
        hbuf[colc] = (hv[t] - mean) * rstd * lng[colc] + lnb[colc];
    }
    __syncthreads();
    #pragma unroll
    for (int t = 0; t < 3; ++t) {
        int colc = tid + t * 256;
        float a = b2[colc];
        for (int k = 0; k < 768; ++k) a += hbuf[k] * w2[k * 768 + colc];
        lat[b * 768 + colc] = a;
    }
}

__global__ void assemble_kernel(const float* __restrict__ lat, const float* __restrict__ cls,
                                const float* __restrict__ P, const float* __restrict__ pos,
                                float* __restrict__ T)
{
    int idx = blockIdx.x * 256 + threadIdx.x;
    if (idx >= 32 * 198 * 768) return;
    int c = idx % 768;
    int row = idx / 768;
    int b = row / 198, t = row % 198;
    float v;
    if (t == 0)      v = lat[b * 768 + c];
    else if (t == 1) v = cls[c];
    else             v = P[((size_t)b * 196 + (t - 2)) * 768 + c];
    T[idx] = v + pos[t * 768 + c];
}

__global__ void sched_kernel(const float* __restrict__ T, const float* __restrict__ sw,
                             const float* __restrict__ sb, const float* __restrict__ budget,
                             int* __restrict__ active)
{
    int b = blockIdx.x, lane = threadIdx.x; // 64 threads
    const float* xr = T + (size_t)b * 198 * 768;
    float acc[6] = {0, 0, 0, 0, 0, 0};
    for (int k = lane; k < 768; k += 64) {
        float xv = xr[k];
        #pragma unroll
        for (int i = 0; i < 6; ++i) acc[i] += xv * sw[k * 6 + i];
    }
    #pragma unroll
    for (int i = 0; i < 6; ++i)
        #pragma unroll
        for (int off = 32; off; off >>= 1) acc[i] += __shfl_xor(acc[i], off);
    if (lane == 0) {
        float lg[6];
        #pragma unroll
        for (int i = 0; i < 6; ++i) lg[i] = acc[i] + sb[i];
        int k = (int)ceilf(budget[b] * 6.f);
        if (k < 1) k = 1;
        for (int i = 0; i < 6; ++i) {
            int rank = 0;
            for (int j = 0; j < 6; ++j)
                rank += (lg[j] > lg[i]) || (lg[j] == lg[i] && j < i);
            active[b * 6 + i] = (rank < k) ? 1 : 0;
        }
    }
}

__global__ void droplat_kernel(const float* __restrict__ T, float* __restrict__ T2)
{
    int idx = blockIdx.x * 256 + threadIdx.x;
    if (idx >= 32 * 197 * 768) return;
    int c = idx % 768;
    int row = idx / 768;
    int b = row / 197, t = row % 197;
    T2[idx] = T[((size_t)b * 198 + t + 1) * 768 + c];
}

__global__ void select_kernel(float* __restrict__ T2, const float* __restrict__ OUT,
                              const int* __restrict__ active, int layer)
{
    int idx = blockIdx.x * 256 + threadIdx.x;
    if (idx >= 32 * 197 * 768) return;
    int b = idx / (197 * 768);
    if (active[b * 6 + layer]) T2[idx] = OUT[idx];
}

__global__ __launch_bounds__(128) void head_kernel(const float* __restrict__ T2,
                                                   const float* __restrict__ g,
                                                   const float* __restrict__ bta,
                                                   const float* __restrict__ hw,
                                                   const float* __restrict__ hb,
                                                   float* __restrict__ out)
{
    int b = blockIdx.x, tid = threadIdx.x;
    __shared__ float hn[768];
    __shared__ float red[128];
    const float* xr = T2 + (size_t)b * 197 * 768;
    float v[6];
    float s = 0.f;
    #pragma unroll
    for (int i = 0; i < 6; ++i) { v[i] = xr[tid + i * 128]; s += v[i]; }
    red[tid] = s; __syncthreads();
    for (int o = 64; o > 0; o >>= 1) { if (tid < o) red[tid] += red[tid + o]; __syncthreads(); }
    float mean = red[0] * (1.f / 768.f);
    __syncthreads();
    float vs = 0.f;
    #pragma unroll
    for (int i = 0; i < 6; ++i) { float d = v[i] - mean; vs += d * d; }
    red[tid] = vs; __syncthreads();
    for (int o = 64; o > 0; o >>= 1) { if (tid < o) red[tid] += red[tid + o]; __syncthreads(); }
    float rstd = rsqrtf(red[0] * (1.f / 768.f) + 1e-5f);
    #pragma unroll
    for (int i = 0; i < 6; ++i) {
        int c = tid + i * 128;
        hn[c] = (v[i] - mean) * rstd * g[c] + bta[c];
    }
    __syncthreads();
    if (tid < 100) {
        float a = hb[tid];
        for (int k = 0; k < 768; ++k) a += hn[k] * hw[k * 100 + tid];
        out[b * 100 + tid] = a;
    }
}

// ---------------------------------------------------------------------------
extern "C" void kernel_launch(void* const* d_in, const int* in_sizes, int n_in,
                              void* d_out, int out_size, void* d_ws, size_t ws_size,
                              hipStream_t stream)
{
    const float* x        = (const float*)d_in[0];
    const float* budget   = (const float*)d_in[1];
    const float* pe_table = (const float*)d_in[2];
    const float* lat_w1   = (const float*)d_in[3];
    const float* lat_b1   = (const float*)d_in[4];
    const float* lat_ln_g = (const float*)d_in[5];
    const float* lat_ln_b = (const float*)d_in[6];
    const float* lat_w2   = (const float*)d_in[7];
    const float* lat_b2   = (const float*)d_in[8];
    const float* patch_w  = (const float*)d_in[9];
    const float* patch_b  = (const float*)d_in[10];
    const float* cls_tok  = (const float*)d_in[11];
    const float* pos_emb  = (const float*)d_in[12];
    const float* sched_w  = (const float*)d_in[13];
    const float* sched_b  = (const float*)d_in[14];
    const float* ln1_g    = (const float*)d_in[15];
    const float* ln1_b    = (const float*)d_in[16];
    const float* qkv_w    = (const float*)d_in[17];
    const float* qkv_b    = (const float*)d_in[18];
    const float* proj_w   = (const float*)d_in[19];
    const float* proj_b   = (const float*)d_in[20];
    const float* ln2_g    = (const float*)d_in[21];
    const float* ln2_b    = (const float*)d_in[22];
    const float* fc1_w    = (const float*)d_in[23];
    const float* fc1_b    = (const float*)d_in[24];
    const float* fc2_w    = (const float*)d_in[25];
    const float* fc2_b    = (const float*)d_in[26];
    const float* norm_g   = (const float*)d_in[27];
    const float* norm_b   = (const float*)d_in[28];
    const float* head_w   = (const float*)d_in[29];
    const float* head_b   = (const float*)d_in[30];
    float* out = (float*)d_out;
    (void)in_sizes; (void)n_in; (void)out_size; (void)ws_size;

    char* ws = (char*)d_ws;
    size_t off = 0;
    auto alloc = [&](size_t bytes) -> char* {
        char* p = ws + off;
        off = (off + bytes + 255) & ~(size_t)255;
        return p;
    };
    float* pw2  = (float*)alloc(768ull * 768 * 4);     // patch_w transposed (K,N)
    float* Ap   = (float*)alloc(6272ull * 768 * 4);
    float* P    = (float*)alloc(6272ull * 768 * 4);
    float* T    = (float*)alloc(6400ull * 768 * 4);    // padded to 6400 rows
    float* T2   = (float*)alloc(6400ull * 768 * 4);
    float* H    = (float*)alloc(6400ull * 768 * 4);
    float* QKV  = (float*)alloc(6336ull * 2304 * 4);
    float* O    = (float*)alloc(6400ull * 768 * 4);
    float* MLP1 = (float*)alloc(6400ull * 3072 * 4);
    float* OUT  = (float*)alloc(6400ull * 768 * 4);
    float* lat  = (float*)alloc(32ull * 768 * 4);
    int*   act  = (int*)alloc(32 * 6 * 4);

    // --- patch embed + latent + token assembly
    trans_pw_kernel<<<dim3(24, 24), 256, 0, stream>>>(patch_w, pw2);
    im2col_kernel<<<(6272 * 768 + 255) / 256, 256, 0, stream>>>(x, Ap);
    latent_kernel<<<32, 256, 0, stream>>>(pe_table, budget, lat_w1, lat_b1,
                                          lat_ln_g, lat_ln_b, lat_w2, lat_b2, lat);
    gemm32_kernel<false, false><<<dim3(6, 49), 256, 0, stream>>>(
        Ap, pw2, patch_b, nullptr, P, 6272, 768, 768);
    assemble_kernel<<<(32 * 198 * 768 + 255) / 256, 256, 0, stream>>>(lat, cls_tok, P, pos_emb, T);

    // --- 6 fixed blocks (S=198, M=6336), residual in place
    for (int l = 0; l < 6; ++l) {
        ln_kernel<<<6336 / 4, 256, 0, stream>>>(T, ln1_g + l * 768, ln1_b + l * 768, H, 6336);
        gemm32_kernel<false, false><<<dim3(18, 50), 256, 0, stream>>>(
            H, qkv_w + (size_t)l * 768 * 2304, qkv_b + l * 2304, nullptr, QKV, 6336, 2304, 768);
        attn_kernel<<<384, 256, 0, stream>>>(QKV, O, 198);
        gemm32_kernel<false, true><<<dim3(6, 50), 256, 0, stream>>>(
            O, proj_w + (size_t)l * 768 * 768, proj_b + l * 768, T, T, 6336, 768, 768);
        ln_kernel<<<6336 / 4, 256, 0, stream>>>(T, ln2_g + l * 768, ln2_b + l * 768, H, 6336);
        gemm32_kernel<true, false><<<dim3(24, 50), 256, 0, stream>>>(
            H, fc1_w + (size_t)l * 768 * 3072, fc1_b + l * 3072, nullptr, MLP1, 6336, 3072, 768);
        gemm32_kernel<false, true><<<dim3(6, 50), 256, 0, stream>>>(
            MLP1, fc2_w + (size_t)l * 3072 * 768, fc2_b + l * 768, T, T, 6336, 768, 3072);
    }

    // --- scheduler + drop lat token
    sched_kernel<<<32, 64, 0, stream>>>(T, sched_w, sched_b, budget, act);
    droplat_kernel<<<(32 * 197 * 768 + 255) / 256, 256, 0, stream>>>(T, T2);

    // --- 6 adaptive blocks (S=197, M=6304), full compute then gated merge
    for (int i = 0; i < 6; ++i) {
        int l = 6 + i;
        ln_kernel<<<6304 / 4, 256, 0, stream>>>(T2, ln1_g + l * 768, ln1_b + l * 768, H, 6304);
        gemm32_kernel<false, false><<<dim3(18, 50), 256, 0, stream>>>(
            H, qkv_w + (size_t)l * 768 * 2304, qkv_b + l * 2304, nullptr, QKV, 6304, 2304, 768);
        attn_kernel<<<384, 256, 0, stream>>>(QKV, O, 197);
        gemm32_kernel<false, true><<<dim3(6, 50), 256, 0, stream>>>(
            O, proj_w + (size_t)l * 768 * 768, proj_b + l * 768, T2, OUT, 6304, 768, 768);
        ln_kernel<<<6304 / 4, 256, 0, stream>>>(OUT, ln2_g + l * 768, ln2_b + l * 768, H, 6304);
        gemm32_kernel<true, false><<<dim3(24, 50), 256, 0, stream>>>(
            H, fc1_w + (size_t)l * 768 * 3072, fc1_b + l * 3072, nullptr, MLP1, 6304, 3072, 768);
        gemm32_kernel<false, true><<<dim3(6, 50), 256, 0, stream>>>(
            MLP1, fc2_w + (size_t)l * 3072 * 768, fc2_b + l * 768, OUT, OUT, 6304, 768, 3072);
        select_kernel<<<(32 * 197 * 768 + 255) / 256, 256, 0, stream>>>(T2, OUT, act, i);
    }

    // --- final LN + head
    head_kernel<<<32, 128, 0, stream>>>(T2, norm_g, norm_b, head_w, head_b, out);
}

// Round 3
// 8317.798 us; speedup vs baseline: 1.8197x; 1.8197x over previous
//
#include <hip/hip_runtime.h>
#include <hip/hip_bf16.h>
#include <math.h>

// AdaptiveViT forward. GEMMs: emulated-fp32 via PRE-SPLIT bf16 hi/lo planes and
// 3x MFMA 16x16x32 (ah*bh + al*bh + ah*bl). Split is done once per operand by
// producers (LN / attn / gelu epilogue / weight transpose), never in the K-loop.
// Weights are transposed+split per layer into a reused (N,K) plane slot.
// Residual stream / LN / softmax / attention in fp32.

using bf16   = __hip_bfloat16;
using short8 = __attribute__((ext_vector_type(8))) short;
using f32x4  = __attribute__((ext_vector_type(4))) float;

#define GLD16(gptr, lptr)                                                            \
    __builtin_amdgcn_global_load_lds((const __attribute__((address_space(1))) void*)(gptr), \
                                     (__attribute__((address_space(3))) void*)(lptr), 16, 0, 0)

// split f32 -> bf16 hi (RNE) + bf16 lo (truncated residual)
__device__ __forceinline__ void split2(float x, short& h, short& l)
{
    unsigned u  = __float_as_uint(x);
    unsigned hr = (u + 0x7fffu + ((u >> 16) & 1u)) & 0xffff0000u;
    h = (short)(hr >> 16);
    float res = x - __uint_as_float(hr);
    l = (short)(__float_as_uint(res) >> 16);
}

// ---------------------------------------------------------------------------
// W (K,N) f32 -> Wh/Wl (N,K) bf16 planes (transpose + split)
__global__ __launch_bounds__(256) void trans_split_kernel(const float* __restrict__ W,
                                                          short* __restrict__ Wh,
                                                          short* __restrict__ Wl,
                                                          int K, int N)
{
    __shared__ float tile[32][33];
    int n0 = blockIdx.x * 32, k0 = blockIdx.y * 32;
    int c = threadIdx.x & 31, r = threadIdx.x >> 5;
    #pragma unroll
    for (int i = 0; i < 32; i += 8)
        tile[r + i][c] = W[(size_t)(k0 + r + i) * N + n0 + c];
    __syncthreads();
    #pragma unroll
    for (int i = 0; i < 32; i += 8) {
        short h, l; split2(tile[c][r + i], h, l);
        size_t o = (size_t)(n0 + r + i) * K + k0 + c;
        Wh[o] = h; Wl[o] = l;
    }
}

// elementwise f32 -> hi/lo planes (for patch_w, already (N,K))
__global__ void split_kernel(const float* __restrict__ in, short* __restrict__ h,
                             short* __restrict__ l, int n)
{
    int i = blockIdx.x * 256 + threadIdx.x;
    if (i >= n) return;
    short hh, ll; split2(in[i], hh, ll);
    h[i] = hh; l[i] = ll;
}

// im2col + split: A[(b*196+p)][c*256+i*16+j] = x[b][c][py*16+i][px*16+j]
__global__ void im2col_split_kernel(const float* __restrict__ x,
                                    short* __restrict__ Ah, short* __restrict__ Al)
{
    int idx = blockIdx.x * 256 + threadIdx.x;
    if (idx >= 6272 * 768) return;
    int k = idx % 768;
    int row = idx / 768;
    int b = row / 196, p = row % 196;
    int py = p / 14, px = p % 14;
    int c = k >> 8, rem = k & 255;
    int i = rem >> 4, j = rem & 15;
    float v = x[(((size_t)b * 3 + c) * 224 + py * 16 + i) * 224 + px * 16 + j];
    short h, l; split2(v, h, l);
    Ah[idx] = h; Al[idx] = l;
}

// ---------------------------------------------------------------------------
// Emulated-fp32 GEMM on pre-split planes:
// C(MxN) = (Ah+Al)(MxK) @ (Bh+Bl)(NxK)^T + bias [+resid] [gelu] [split-out].
// 128x128 tile, BK=32, 4 waves of 64x64, global_load_lds width-16 staging,
// contiguous ds_read_b128 fragments, 3 MFMAs per cell.
template<bool GELU, bool RES, bool SPLITOUT>
__global__ __launch_bounds__(256) void gemm3_kernel(const short* __restrict__ Ah,
                                                    const short* __restrict__ Al,
                                                    const short* __restrict__ Bh,
                                                    const short* __restrict__ Bl,
                                                    const float* __restrict__ bias,
                                                    const float* __restrict__ resid,
                                                    float* __restrict__ Cf,
                                                    short* __restrict__ Ch,
                                                    short* __restrict__ Cl,
                                                    int M, int N, int K)
{
    __shared__ __align__(16) short Ash[128 * 32];
    __shared__ __align__(16) short Asl[128 * 32];
    __shared__ __align__(16) short Bsh[128 * 32];
    __shared__ __align__(16) short Bsl[128 * 32];
    const int tid  = threadIdx.x;
    const int lane = tid & 63;
    const int w    = tid >> 6;
    const int wm   = w >> 1, wn = w & 1;
    const int m0   = blockIdx.y * 128;
    const int n0   = blockIdx.x * 128;
    const int col  = lane & 15;
    const int quad = lane >> 4;
    const int srow = lane >> 2;        // staging row within 16-row chunk
    const int skc  = (lane & 3) * 8;   // staging k offset (bf16 elems)

    f32x4 acc[4][4];
    #pragma unroll
    for (int i = 0; i < 4; ++i)
        #pragma unroll
        for (int j = 0; j < 4; ++j) acc[i][j] = (f32x4)0.f;

    const short* Ahb = Ah + (size_t)m0 * K;
    const short* Alb = Al + (size_t)m0 * K;
    const short* Bhb = Bh + (size_t)n0 * K;
    const short* Blb = Bl + (size_t)n0 * K;

    for (int k0 = 0; k0 < K; k0 += 32) {
        #pragma unroll
        for (int i = 0; i < 2; ++i) {
            int r = w * 32 + i * 16;
            size_t go = (size_t)(r + srow) * K + k0 + skc;
            GLD16(Ahb + go, &Ash[r * 32]);
            GLD16(Alb + go, &Asl[r * 32]);
            GLD16(Bhb + go, &Bsh[r * 32]);
            GLD16(Blb + go, &Bsl[r * 32]);
        }
        __syncthreads();
        short8 ah[4], al[4];
        #pragma unroll
        for (int mi = 0; mi < 4; ++mi) {
            int ao = (wm * 64 + mi * 16 + col) * 32 + quad * 8;
            ah[mi] = *(const short8*)&Ash[ao];
            al[mi] = *(const short8*)&Asl[ao];
        }
        #pragma unroll
        for (int ni = 0; ni < 4; ++ni) {
            int bo = (wn * 64 + ni * 16 + col) * 32 + quad * 8;
            short8 bh = *(const short8*)&Bsh[bo];
            short8 bl = *(const short8*)&Bsl[bo];
            #pragma unroll
            for (int mi = 0; mi < 4; ++mi) {
                acc[mi][ni] = __builtin_amdgcn_mfma_f32_16x16x32_bf16(ah[mi], bh, acc[mi][ni], 0, 0, 0);
                acc[mi][ni] = __builtin_amdgcn_mfma_f32_16x16x32_bf16(al[mi], bh, acc[mi][ni], 0, 0, 0);
                acc[mi][ni] = __builtin_amdgcn_mfma_f32_16x16x32_bf16(ah[mi], bl, acc[mi][ni], 0, 0, 0);
            }
        }
        __syncthreads();
    }

    #pragma unroll
    for (int mi = 0; mi < 4; ++mi) {
        #pragma unroll
        for (int ni = 0; ni < 4; ++ni) {
            int gcol = n0 + wn * 64 + ni * 16 + col;
            float bv = bias[gcol];
            #pragma unroll
            for (int r = 0; r < 4; ++r) {
                int grow = m0 + wm * 64 + mi * 16 + quad * 4 + r;
                if (grow < M) {
                    float v = acc[mi][ni][r] + bv;
                    if (RES) v += resid[(size_t)grow * N + gcol];
                    if (GELU) v = 0.5f * v * (1.f + erff(v * 0.70710678118654752f));
                    size_t o = (size_t)grow * N + gcol;
                    if (SPLITOUT) { short h, l; split2(v, h, l); Ch[o] = h; Cl[o] = l; }
                    else          Cf[o] = v;
                }
            }
        }
    }
}

// ---------------------------------------------------------------------------
// LayerNorm over 768, fp32 in -> bf16 hi/lo planes. One wave per row.
__global__ __launch_bounds__(256) void ln_kernel(const float* __restrict__ x,
                                                 const float* __restrict__ g,
                                                 const float* __restrict__ bta,
                                                 short* __restrict__ outh,
                                                 short* __restrict__ outl, int M)
{
    int row = blockIdx.x * 4 + (threadIdx.x >> 6);
    int lane = threadIdx.x & 63;
    if (row >= M) return;
    const float* xr = x + (size_t)row * 768;
    float vals[12];
    float s = 0.f;
    #pragma unroll
    for (int i = 0; i < 12; ++i) { vals[i] = xr[lane + i * 64]; s += vals[i]; }
    #pragma unroll
    for (int off = 32; off; off >>= 1) s += __shfl_xor(s, off);
    float mean = s * (1.f / 768.f);
    float vs = 0.f;
    #pragma unroll
    for (int i = 0; i < 12; ++i) { float d = vals[i] - mean; vs += d * d; }
    #pragma unroll
    for (int off = 32; off; off >>= 1) vs += __shfl_xor(vs, off);
    float rstd = rsqrtf(vs * (1.f / 768.f) + 1e-5f);
    size_t rb = (size_t)row * 768;
    #pragma unroll
    for (int i = 0; i < 12; ++i) {
        int c = lane + i * 64;
        short h, l; split2((vals[i] - mean) * rstd * g[c] + bta[c], h, l);
        outh[rb + c] = h; outl[rb + c] = l;
    }
}

// ---------------------------------------------------------------------------
// Attention: one block per (b, head), fp32, online softmax, one query row/thread.
__global__ __launch_bounds__(256) void attn_kernel(const float* __restrict__ qkv,
                                                   short* __restrict__ Oh,
                                                   short* __restrict__ Ol, int S)
{
    __shared__ float Ks[128 * 64];
    __shared__ float Vs[128 * 64];
    int bh = blockIdx.x;
    int b = bh / 12, h = bh % 12;
    const float* base = qkv + (size_t)b * S * 2304;
    int tid = threadIdx.x;
    int r = tid;
    bool act = (r < S);
    float q[64];
    #pragma unroll
    for (int d = 0; d < 64; ++d) q[d] = 0.f;
    if (act) {
        const float4* qp = (const float4*)(base + (size_t)r * 2304 + h * 64);
        #pragma unroll
        for (int d4 = 0; d4 < 16; ++d4) {
            float4 t = qp[d4];
            q[4 * d4] = t.x; q[4 * d4 + 1] = t.y; q[4 * d4 + 2] = t.z; q[4 * d4 + 3] = t.w;
        }
    }
    float o[64];
    #pragma unroll
    for (int d = 0; d < 64; ++d) o[d] = 0.f;
    float m = -1e30f, l = 0.f;

    for (int jc = 0; jc < S; jc += 128) {
        int cnt = min(128, S - jc);
        __syncthreads();
        for (int idx = tid; idx < cnt * 64; idx += 256) {
            int j = idx >> 6, d = idx & 63;
            const float* rp = base + (size_t)(jc + j) * 2304 + h * 64 + d;
            Ks[idx] = rp[768];
            Vs[idx] = rp[1536];
        }
        __syncthreads();
        if (act) {
            for (int j = 0; j < cnt; ++j) {
                const float4* kr = (const float4*)&Ks[j * 64];
                float s0 = 0.f, s1 = 0.f, s2 = 0.f, s3 = 0.f;
                #pragma unroll
                for (int d4 = 0; d4 < 16; ++d4) {
                    float4 kv = kr[d4];
                    s0 += q[4 * d4]     * kv.x;
                    s1 += q[4 * d4 + 1] * kv.y;
                    s2 += q[4 * d4 + 2] * kv.z;
                    s3 += q[4 * d4 + 3] * kv.w;
                }
                float s = ((s0 + s1) + (s2 + s3)) * 0.125f;
                float mn = fmaxf(m, s);
                float alpha = expf(m - mn);
                float p = expf(s - mn);
                l = l * alpha + p;
                m = mn;
                const float4* vr = (const float4*)&Vs[j * 64];
                #pragma unroll
                for (int d4 = 0; d4 < 16; ++d4) {
                    float4 vv = vr[d4];
                    o[4 * d4]     = o[4 * d4]     * alpha + p * vv.x;
                    o[4 * d4 + 1] = o[4 * d4 + 1] * alpha + p * vv.y;
                    o[4 * d4 + 2] = o[4 * d4 + 2] * alpha + p * vv.z;
                    o[4 * d4 + 3] = o[4 * d4 + 3] * alpha + p * vv.w;
                }
            }
        }
    }
    if (act) {
        float inv = 1.f / l;
        size_t rb = (size_t)(b * S + r) * 768 + h * 64;
        #pragma unroll
        for (int d = 0; d < 64; ++d) {
            short hh, ll; split2(o[d] * inv, hh, ll);
            Oh[rb + d] = hh; Ol[rb + d] = ll;
        }
    }
}

// ---------------------------------------------------------------------------
__global__ __launch_bounds__(256) void latent_kernel(const float* __restrict__ pe_table,
                                                     const float* __restrict__ budget,
                                                     const float* __restrict__ w1, const float* __restrict__ b1,
                                                     const float* __restrict__ lng, const float* __restrict__ lnb,
                                                     const float* __restrict__ w2, const float* __restrict__ b2,
                                                     float* __restrict__ lat)
{
    int b = blockIdx.x, tid = threadIdx.x;
    __shared__ float pe[256];
    __shared__ float hbuf[768];
    __shared__ float red[256];
    int idx = (int)rintf(budget[b] * 99.f);
    pe[tid] = pe_table[idx * 256 + tid];
    __syncthreads();
    float hv[3];
    #pragma unroll
    for (int t = 0; t < 3; ++t) {
        int colc = tid + t * 256;
        float a = b1[colc];
        for (int k = 0; k < 256; ++k) a += pe[k] * w1[k * 768 + colc];
        hv[t] = 0.5f * a * (1.f + erff(a * 0.70710678118654752f));
    }
    float s = hv[0] + hv[1] + hv[2];
    red[tid] = s; __syncthreads();
    for (int o = 128; o > 0; o >>= 1) { if (tid < o) red[tid] += red[tid + o]; __syncthreads(); }
    float mean = red[0] * (1.f / 768.f);
    __syncthreads();
    float vs = 0.f;
    #pragma unroll
    for (int t = 0; t < 3; ++t) { float d = hv[t] - mean; vs += d * d; }
    red[tid] = vs; __syncthreads();
    for (int o = 128; o > 0; o >>= 1) { if (tid < o) red[tid] += red[tid + o]; __syncthreads(); }
    float rstd = rsqrtf(red[0] * (1.f / 768.f) + 1e-5f);
    __syncthreads();
    #pragma unroll
    for (int t = 0; t < 3; ++t) {
        int colc = tid + t * 256;
        hbuf[colc] = (hv[t] - mean) * rstd * lng[colc] + lnb[colc];
    }
    __syncthreads();
    #pragma unroll
    for (int t = 0; t < 3; ++t) {
        int colc = tid + t * 256;
        float a = b2[colc];
        for (int k = 0; k < 768; ++k) a += hbuf[k] * w2[k * 768 + colc];
        lat[b * 768 + colc] = a;
    }
}

__global__ void assemble_kernel(const float* __restrict__ lat, const float* __restrict__ cls,
                                const float* __restrict__ P, const float* __restrict__ pos,
                                float* __restrict__ T)
{
    int idx = blockIdx.x * 256 + threadIdx.x;
    if (idx >= 32 * 198 * 768) return;
    int c = idx % 768;
    int row = idx / 768;
    int b = row / 198, t = row % 198;
    float v;
    if (t == 0)      v = lat[b * 768 + c];
    else if (t == 1) v = cls[c];
    else             v = P[((size_t)b * 196 + (t - 2)) * 768 + c];
    T[idx] = v + pos[t * 768 + c];
}

__global__ void sched_kernel(const float* __restrict__ T, const float* __restrict__ sw,
                             const float* __restrict__ sb, const float* __restrict__ budget,
                             int* __restrict__ active)
{
    int b = blockIdx.x, lane = threadIdx.x; // 64 threads
    const float* xr = T + (size_t)b * 198 * 768;
    float acc[6] = {0, 0, 0, 0, 0, 0};
    for (int k = lane; k < 768; k += 64) {
        float xv = xr[k];
        #pragma unroll
        for (int i = 0; i < 6; ++i) acc[i] += xv * sw[k * 6 + i];
    }
    #pragma unroll
    for (int i = 0; i < 6; ++i)
        #pragma unroll
        for (int off = 32; off; off >>= 1) acc[i] += __shfl_xor(acc[i], off);
    if (lane == 0) {
        float lg[6];
        #pragma unroll
        for (int i = 0; i < 6; ++i) lg[i] = acc[i] + sb[i];
        int k = (int)ceilf(budget[b] * 6.f);
        if (k < 1) k = 1;
        for (int i = 0; i < 6; ++i) {
            int rank = 0;
            for (int j = 0; j < 6; ++j)
                rank += (lg[j] > lg[i]) || (lg[j] == lg[i] && j < i);
            active[b * 6 + i] = (rank < k) ? 1 : 0;
        }
    }
}

__global__ void droplat_kernel(const float* __restrict__ T, float* __restrict__ T2)
{
    int idx = blockIdx.x * 256 + threadIdx.x;
    if (idx >= 32 * 197 * 768) return;
    int c = idx % 768;
    int row = idx / 768;
    int b = row / 197, t = row % 197;
    T2[idx] = T[((size_t)b * 198 + t + 1) * 768 + c];
}

__global__ void select_kernel(float* __restrict__ T2, const float* __restrict__ OUT,
                              const int* __restrict__ active, int layer)
{
    int idx = blockIdx.x * 256 + threadIdx.x;
    if (idx >= 32 * 197 * 768) return;
    int b = idx / (197 * 768);
    if (active[b * 6 + layer]) T2[idx] = OUT[idx];
}

__global__ __launch_bounds__(128) void head_kernel(const float* __restrict__ T2,
                                                   const float* __restrict__ g,
                                                   const float* __restrict__ bta,
                                                   const float* __restrict__ hw,
                                                   const float* __restrict__ hb,
                                                   float* __restrict__ out)
{
    int b = blockIdx.x, tid = threadIdx.x;
    __shared__ float hn[768];
    __shared__ float red[128];
    const float* xr = T2 + (size_t)b * 197 * 768;
    float v[6];
    float s = 0.f;
    #pragma unroll
    for (int i = 0; i < 6; ++i) { v[i] = xr[tid + i * 128]; s += v[i]; }
    red[tid] = s; __syncthreads();
    for (int o = 64; o > 0; o >>= 1) { if (tid < o) red[tid] += red[tid + o]; __syncthreads(); }
    float mean = red[0] * (1.f / 768.f);
    __syncthreads();
    float vs = 0.f;
    #pragma unroll
    for (int i = 0; i < 6; ++i) { float d = v[i] - mean; vs += d * d; }
    red[tid] = vs; __syncthreads();
    for (int o = 64; o > 0; o >>= 1) { if (tid < o) red[tid] += red[tid + o]; __syncthreads(); }
    float rstd = rsqrtf(red[0] * (1.f / 768.f) + 1e-5f);
    #pragma unroll
    for (int i = 0; i < 6; ++i) {
        int c = tid + i * 128;
        hn[c] = (v[i] - mean) * rstd * g[c] + bta[c];
    }
    __syncthreads();
    if (tid < 100) {
        float a = hb[tid];
        for (int k = 0; k < 768; ++k) a += hn[k] * hw[k * 100 + tid];
        out[b * 100 + tid] = a;
    }
}

// ---------------------------------------------------------------------------
extern "C" void kernel_launch(void* const* d_in, const int* in_sizes, int n_in,
                              void* d_out, int out_size, void* d_ws, size_t ws_size,
                              hipStream_t stream)
{
    const float* x        = (const float*)d_in[0];
    const float* budget   = (const float*)d_in[1];
    const float* pe_table = (const float*)d_in[2];
    const float* lat_w1   = (const float*)d_in[3];
    const float* lat_b1   = (const float*)d_in[4];
    const float* lat_ln_g = (const float*)d_in[5];
    const float* lat_ln_b = (const float*)d_in[6];
    const float* lat_w2   = (const float*)d_in[7];
    const float* lat_b2   = (const float*)d_in[8];
    const float* patch_w  = (const float*)d_in[9];
    const float* patch_b  = (const float*)d_in[10];
    const float* cls_tok  = (const float*)d_in[11];
    const float* pos_emb  = (const float*)d_in[12];
    const float* sched_w  = (const float*)d_in[13];
    const float* sched_b  = (const float*)d_in[14];
    const float* ln1_g    = (const float*)d_in[15];
    const float* ln1_b    = (const float*)d_in[16];
    const float* qkv_w    = (const float*)d_in[17];
    const float* qkv_b    = (const float*)d_in[18];
    const float* proj_w   = (const float*)d_in[19];
    const float* proj_b   = (const float*)d_in[20];
    const float* ln2_g    = (const float*)d_in[21];
    const float* ln2_b    = (const float*)d_in[22];
    const float* fc1_w    = (const float*)d_in[23];
    const float* fc1_b    = (const float*)d_in[24];
    const float* fc2_w    = (const float*)d_in[25];
    const float* fc2_b    = (const float*)d_in[26];
    const float* norm_g   = (const float*)d_in[27];
    const float* norm_b   = (const float*)d_in[28];
    const float* head_w   = (const float*)d_in[29];
    const float* head_b   = (const float*)d_in[30];
    float* out = (float*)d_out;
    (void)in_sizes; (void)n_in; (void)out_size; (void)ws_size;

    char* ws = (char*)d_ws;
    size_t off = 0;
    auto alloc = [&](size_t bytes) -> char* {
        char* p = ws + off;
        off = (off + bytes + 255) & ~(size_t)255;
        return p;
    };
    // per-layer weight plane slot (reused across layers)
    short* sQKVh = (short*)alloc(2304ull * 768 * 2);
    short* sQKVl = (short*)alloc(2304ull * 768 * 2);
    short* sPRJh = (short*)alloc(768ull * 768 * 2);
    short* sPRJl = (short*)alloc(768ull * 768 * 2);
    short* sFC1h = (short*)alloc(3072ull * 768 * 2);
    short* sFC1l = (short*)alloc(3072ull * 768 * 2);
    short* sFC2h = (short*)alloc(768ull * 3072 * 2);
    short* sFC2l = (short*)alloc(768ull * 3072 * 2);
    short* pwh   = (short*)alloc(768ull * 768 * 2);
    short* pwl   = (short*)alloc(768ull * 768 * 2);
    float* T     = (float*)alloc(6400ull * 768 * 4);   // padded to 6400 rows
    float* T2    = (float*)alloc(6400ull * 768 * 4);
    float* OUT   = (float*)alloc(6400ull * 768 * 4);
    short* Hh    = (short*)alloc(6400ull * 768 * 2);
    short* Hl    = (short*)alloc(6400ull * 768 * 2);
    float* QKV   = (float*)alloc(6336ull * 2304 * 4);
    short* Oh    = (short*)alloc(6400ull * 768 * 2);
    short* Ol    = (short*)alloc(6400ull * 768 * 2);
    short* Mh    = (short*)alloc(6400ull * 3072 * 2);
    short* Ml    = (short*)alloc(6400ull * 3072 * 2);
    float* lat   = (float*)alloc(32ull * 768 * 4);
    int*   act   = (int*)alloc(32 * 6 * 4);
    float* P     = QKV;          // alias: P consumed before first QKV write
    short* Aph   = Mh;           // alias: im2col planes consumed before first fc1
    short* Apl   = Ml;

    // --- prologue: patch embed + latent + token assembly
    im2col_split_kernel<<<(6272 * 768 + 255) / 256, 256, 0, stream>>>(x, Aph, Apl);
    split_kernel<<<(768 * 768 + 255) / 256, 256, 0, stream>>>(patch_w, pwh, pwl, 768 * 768);
    latent_kernel<<<32, 256, 0, stream>>>(pe_table, budget, lat_w1, lat_b1,
                                          lat_ln_g, lat_ln_b, lat_w2, lat_b2, lat);
    gemm3_kernel<false, false, false><<<dim3(6, 49), 256, 0, stream>>>(
        Aph, Apl, pwh, pwl, patch_b, nullptr, P, nullptr, nullptr, 6272, 768, 768);
    assemble_kernel<<<(32 * 198 * 768 + 255) / 256, 256, 0, stream>>>(lat, cls_tok, P, pos_emb, T);

    // --- 6 fixed blocks (S=198, M=6336)
    for (int l = 0; l < 6; ++l) {
        trans_split_kernel<<<dim3(72, 24), 256, 0, stream>>>(qkv_w + (size_t)l * 768 * 2304, sQKVh, sQKVl, 768, 2304);
        trans_split_kernel<<<dim3(24, 24), 256, 0, stream>>>(proj_w + (size_t)l * 768 * 768, sPRJh, sPRJl, 768, 768);
        trans_split_kernel<<<dim3(96, 24), 256, 0, stream>>>(fc1_w + (size_t)l * 768 * 3072, sFC1h, sFC1l, 768, 3072);
        trans_split_kernel<<<dim3(24, 96), 256, 0, stream>>>(fc2_w + (size_t)l * 3072 * 768, sFC2h, sFC2l, 3072, 768);

        ln_kernel<<<6336 / 4, 256, 0, stream>>>(T, ln1_g + l * 768, ln1_b + l * 768, Hh, Hl, 6336);
        gemm3_kernel<false, false, false><<<dim3(18, 50), 256, 0, stream>>>(
            Hh, Hl, sQKVh, sQKVl, qkv_b + l * 2304, nullptr, QKV, nullptr, nullptr, 6336, 2304, 768);
        attn_kernel<<<384, 256, 0, stream>>>(QKV, Oh, Ol, 198);
        gemm3_kernel<false, true, false><<<dim3(6, 50), 256, 0, stream>>>(
            Oh, Ol, sPRJh, sPRJl, proj_b + l * 768, T, T, nullptr, nullptr, 6336, 768, 768);
        ln_kernel<<<6336 / 4, 256, 0, stream>>>(T, ln2_g + l * 768, ln2_b + l * 768, Hh, Hl, 6336);
        gemm3_kernel<true, false, true><<<dim3(24, 50), 256, 0, stream>>>(
            Hh, Hl, sFC1h, sFC1l, fc1_b + l * 3072, nullptr, nullptr, Mh, Ml, 6336, 3072, 768);
        gemm3_kernel<false, true, false><<<dim3(6, 50), 256, 0, stream>>>(
            Mh, Ml, sFC2h, sFC2l, fc2_b + l * 768, T, T, nullptr, nullptr, 6336, 768, 3072);
    }

    // --- scheduler + drop lat token
    sched_kernel<<<32, 64, 0, stream>>>(T, sched_w, sched_b, budget, act);
    droplat_kernel<<<(32 * 197 * 768 + 255) / 256, 256, 0, stream>>>(T, T2);

    // --- 6 adaptive blocks (S=197, M=6304): full compute then gated merge
    for (int i = 0; i < 6; ++i) {
        int l = 6 + i;
        trans_split_kernel<<<dim3(72, 24), 256, 0, stream>>>(qkv_w + (size_t)l * 768 * 2304, sQKVh, sQKVl, 768, 2304);
        trans_split_kernel<<<dim3(24, 24), 256, 0, stream>>>(proj_w + (size_t)l * 768 * 768, sPRJh, sPRJl, 768, 768);
        trans_split_kernel<<<dim3(96, 24), 256, 0, stream>>>(fc1_w + (size_t)l * 768 * 3072, sFC1h, sFC1l, 768, 3072);
        trans_split_kernel<<<dim3(24, 96), 256, 0, stream>>>(fc2_w + (size_t)l * 3072 * 768, sFC2h, sFC2l, 3072, 768);

        ln_kernel<<<6304 / 4, 256, 0, stream>>>(T2, ln1_g + l * 768, ln1_b + l * 768, Hh, Hl, 6304);
        gemm3_kernel<false, false, false><<<dim3(18, 50), 256, 0, stream>>>(
            Hh, Hl, sQKVh, sQKVl, qkv_b + l * 2304, nullptr, QKV, nullptr, nullptr, 6304, 2304, 768);
        attn_kernel<<<384, 256, 0, stream>>>(QKV, Oh, Ol, 197);
        gemm3_kernel<false, true, false><<<dim3(6, 50), 256, 0, stream>>>(
            Oh, Ol, sPRJh, sPRJl, proj_b + l * 768, T2, OUT, nullptr, nullptr, 6304, 768, 768);
        ln_kernel<<<6304 / 4, 256, 0, stream>>>(OUT, ln2_g + l * 768, ln2_b + l * 768, Hh, Hl, 6304);
        gemm3_kernel<true, false, true><<<dim3(24, 50), 256, 0, stream>>>(
            Hh, Hl, sFC1h, sFC1l, fc1_b + l * 3072, nullptr, nullptr, Mh, Ml, 6304, 3072, 768);
        gemm3_kernel<false, true, false><<<dim3(6, 50), 256, 0, stream>>>(
            Mh, Ml, sFC2h, sFC2l, fc2_b + l * 768, OUT, OUT, nullptr, nullptr, 6304, 768, 3072);
        select_kernel<<<(32 * 197 * 768 + 255) / 256, 256, 0, stream>>>(T2, OUT, act, i);
    }

    // --- final LN + head
    head_kernel<<<32, 128, 0, stream>>>(T2, norm_g, norm_b, head_w, head_b, out);
}